// Round 6
// baseline (345.555 us; speedup 1.0000x reference)
//
#include <hip/hip_runtime.h>
#include <math.h>

namespace {

typedef __bf16 bf16x8 __attribute__((ext_vector_type(8)));
typedef float  f32x4  __attribute__((ext_vector_type(4)));

constexpr int B_      = 65536;
constexpr int OBS_DIM_= 85;
constexpr int NL_     = 5;
constexpr int NT_     = 10;
constexpr int HID_    = 64;
constexpr int NACT_   = 5;
constexpr float ALPHA_= 0.01f;

__device__ __forceinline__ float leaky(float x)    { return x > 0.0f ? x : ALPHA_ * x; }
__device__ __forceinline__ float sigmoidf(float x) { return 1.0f / (1.0f + __expf(-x)); }
__device__ __forceinline__ float tanh_fast(float x){ return 1.0f - 2.0f / (__expf(2.0f * x) + 1.0f); }

// ---------------------------------------------------------------------------
// Prep: Wa = W@a  ((h_mix@W)@a == h_mix@(W@a): kills the 64x64 matmul), plus
// bf16 weights for the MFMA kernel. ws: [0,512) Wa f32; Wih; Whh; Wf1T(64x96).
// ---------------------------------------------------------------------------
__global__ void prep_kernel(const float* __restrict__ W, const float* __restrict__ a,
                            const float* __restrict__ w_ih, const float* __restrict__ w_hh,
                            const float* __restrict__ w_fc1, void* __restrict__ ws) {
  float* Wa   = (float*)ws;
  __bf16* ih  = (__bf16*)((char*)ws + 512);
  __bf16* hh  = ih + 192 * 64;
  __bf16* f1t = hh + 192 * 64;
  const int tid = blockIdx.x * 256 + threadIdx.x;
  if (blockIdx.x == 0 && threadIdx.x < 64) {
    const int i = threadIdx.x;
    float s1 = 0.0f, s2 = 0.0f;
    #pragma unroll
    for (int j = 0; j < 64; ++j) {
      float w = W[i * 64 + j];
      s1 += w * a[j];
      s2 += w * a[64 + j];
    }
    Wa[i] = s1;
    Wa[64 + i] = s2;
  }
  const int stride = gridDim.x * 256;
  for (int i = tid; i < 192 * 64; i += stride) {
    ih[i] = (__bf16)w_ih[i];
    hh[i] = (__bf16)w_hh[i];
  }
  for (int i = tid; i < 64 * 96; i += stride) {
    int n = i / 96, k = i - 96 * n;
    f1t[i] = (__bf16)(k < 90 ? w_fc1[k * 64 + n] : 0.0f);
  }
}

// ======================= FRONT KERNEL =======================
// 16 lanes cooperate per row; each lane owns 4 of the 64 INF units.
constexpr int FROWS_ = 16;    // rows per block (4 waves x 4 rows)
constexpr int SOBS_  = 88;    // f32 row stride: 352B -> 16B aligned; rows hit disjoint banks

// stage1 for t in [T0,T1): lane owns units u0..u0+3. Weights as f32x4 regs
// (8 coalesced vector loads from global, 32 VGPR live only inside this call).
template <int T0, int T1>
__device__ __forceinline__ void stage1v(const float* __restrict__ wc,
                                        const float* __restrict__ bc,
                                        const float* orow, int u0,
                                        const float* wa1, const float* wa2,
                                        float (&p1)[NT_], float (&p2)[NT_]) {
  f32x4 w4[8];
  #pragma unroll
  for (int f = 0; f < 8; ++f) w4[f] = *(const f32x4*)&wc[f * 64 + u0];
  const f32x4 bb = *(const f32x4*)&bc[u0];
  #pragma unroll
  for (int t = T0; t < T1; ++t) {
    const int ia = t * 8 + 4;            // f=0..3: never wraps (8t+7 <= 79)
    const int ib = (t * 8 + 8) % 80;     // f=4..7: wraps only at t=9 -> 0..3
    f32x4 oa = *(const f32x4*)&orow[ia];
    f32x4 ob = *(const f32x4*)&orow[ib];
    float a1 = 0.0f, a2 = 0.0f;
    #pragma unroll
    for (int j = 0; j < 4; ++j) {
      float z = bb[j];
      z += oa[0] * w4[0][j] + oa[1] * w4[1][j] + oa[2] * w4[2][j] + oa[3] * w4[3][j];
      z += ob[0] * w4[4][j] + ob[1] * w4[5][j] + ob[2] * w4[6][j] + ob[3] * w4[7][j];
      float hm = leaky(z);
      a1 += hm * wa1[j];
      a2 += hm * wa2[j];
    }
    p1[t] = a1; p2[t] = a2;
  }
}

__global__ __attribute__((amdgpu_waves_per_eu(4, 4))) __launch_bounds__(256)
void front_kernel(
    const float* __restrict__ obs,
    const float* __restrict__ w_in0, const float* __restrict__ b_in0,
    const float* __restrict__ w_in1, const float* __restrict__ b_in1,
    const float* __restrict__ w_in2, const float* __restrict__ b_in2,
    const float* __restrict__ w_o1, const float* __restrict__ b_o1,
    const float* __restrict__ w_o2, const float* __restrict__ b_o2,
    const float* __restrict__ w_o3, const float* __restrict__ b_o3,
    const float* __restrict__ Wa,
    float* __restrict__ out5) {

  __shared__ __align__(16) float s_obs[FROWS_][SOBS_];

  const int tid = threadIdx.x;
  const long gr0 = (long)blockIdx.x * FROWS_;

  // stage obs cols 0..79 (stage-1 needs only the first 80)
  {
    const float* src = obs + gr0 * OBS_DIM_;
    for (int idx = tid; idx < FROWS_ * 80; idx += 256) {
      int r = idx / 80, c = idx - 80 * r;
      s_obs[r][c] = src[r * OBS_DIM_ + c];
    }
  }
  __syncthreads();

  const int lane = tid & 63;
  const int sub  = lane & 15;                 // 0..15: unit-slice owner
  const int rloc = ((tid >> 6) << 2) + (lane >> 4);   // 4 rows per wave
  const int u0   = sub * 4;
  const float* orow = s_obs[rloc];

  float wa1[4], wa2[4];
  #pragma unroll
  for (int j = 0; j < 4; ++j) { wa1[j] = Wa[u0 + j]; wa2[j] = Wa[64 + u0 + j]; }

  float p1[NT_], p2[NT_];
  stage1v<0, 5>(w_in0, b_in0, orow, u0, wa1, wa2, p1, p2);
  stage1v<5, 9>(w_in1, b_in1, orow, u0, wa1, wa2, p1, p2);
  stage1v<9, 10>(w_in2, b_in2, orow, u0, wa1, wa2, p1, p2);

  // butterfly over the 16-lane group -> all lanes hold full Wh1/Wh2
  #pragma unroll
  for (int m = 1; m < 16; m <<= 1) {
    #pragma unroll
    for (int t = 0; t < NT_; ++t) {
      p1[t] += __shfl_xor(p1[t], m, 64);
      p2[t] += __shfl_xor(p2[t], m, 64);
    }
  }

  // att1 column softmax stats (shared across rows)
  float colm[NL_], cols_[NL_];
  #pragma unroll
  for (int jj = 0; jj < NL_; ++jj) {
    float ev[NL_], m = -1e30f;
    #pragma unroll
    for (int k = 0; k < NL_; ++k) { ev[k] = leaky(p1[NL_ + jj] + p2[k]); m = fmaxf(m, ev[k]); }
    float s = 0.0f;
    #pragma unroll
    for (int k = 0; k < NL_; ++k) s += __expf(ev[k] - m);
    colm[jj] = m; cols_[jj] = s;
  }

  // lanes sub<5: one attention row each. All MLP weight reads are wave-uniform
  // -> scalar s_load pipe. h1 fused into h2acc (no h1v[32] array).
  float hp_local = 0.0f;
  if (sub < NL_) {
    const int r = sub;
    float wh1_r = p1[0], wh2_r = p2[0];
    if (r == 1) { wh1_r = p1[1]; wh2_r = p2[1]; }
    if (r == 2) { wh1_r = p1[2]; wh2_r = p2[2]; }
    if (r == 3) { wh1_r = p1[3]; wh2_r = p2[3]; }
    if (r == 4) { wh1_r = p1[4]; wh2_r = p2[4]; }
    float att[NT_];
    {
      float ev[NL_], m = -1e30f;
      #pragma unroll
      for (int j = 0; j < NL_; ++j) { ev[j] = leaky(wh1_r + p2[NL_ + j]); m = fmaxf(m, ev[j]); }
      float s = 0.0f;
      #pragma unroll
      for (int j = 0; j < NL_; ++j) { float e = __expf(ev[j] - m); att[j] = e; s += e; }
      float inv = 1.0f / s;
      #pragma unroll
      for (int j = 0; j < NL_; ++j) att[j] *= inv;
      #pragma unroll
      for (int jj = 0; jj < NL_; ++jj) {
        float e = leaky(p1[NL_ + jj] + wh2_r);
        att[NL_ + jj] = __expf(e - colm[jj]) / cols_[jj];
      }
    }
    float h2acc[16];
    #pragma unroll
    for (int c2 = 0; c2 < 16; ++c2) h2acc[c2] = 0.0f;
    #pragma unroll
    for (int c = 0; c < 32; ++c) {
      float z = b_o1[c];
      #pragma unroll
      for (int k = 0; k < NT_; ++k) z += att[k] * w_o1[k * 32 + c];
      float h1 = leaky(z);
      #pragma unroll
      for (int c2 = 0; c2 < 16; ++c2) h2acc[c2] += h1 * w_o2[c * 16 + c2];
    }
    float z3 = b_o3[0];
    #pragma unroll
    for (int c2 = 0; c2 < 16; ++c2) z3 += leaky(h2acc[c2] + b_o2[c2]) * w_o3[c2];
    hp_local = leaky(z3);
  }

  // gather hp from lanes 0..4 of the 16-lane group, softmax
  const int base = lane & ~15;
  float hp[NL_];
  #pragma unroll
  for (int k = 0; k < NL_; ++k) hp[k] = __shfl(hp_local, base + k, 64);
  float m5 = hp[0];
  #pragma unroll
  for (int j = 1; j < NL_; ++j) m5 = fmaxf(m5, hp[j]);
  float ex[NL_], ssum = 0.0f;
  #pragma unroll
  for (int j = 0; j < NL_; ++j) { ex[j] = __expf(hp[j] - m5); ssum += ex[j]; }
  const float sinv = 1.0f / ssum;

  if (sub < NL_) {
    float ow = ex[0];
    if (sub == 1) ow = ex[1];
    if (sub == 2) ow = ex[2];
    if (sub == 3) ow = ex[3];
    if (sub == 4) ow = ex[4];
    out5[(gr0 + rloc) * NL_ + sub] = ow * sinv;
  }
}

// ======================= GEMM KERNEL (validated MFMA phase) =======================
constexpr int ROWS_ = 64;     // 4 waves x 16-row tiles
constexpr int SOB_  = 104;    // bf16 stride: 208B -> 2-way alias (free)
constexpr int SXH_  = 72;     // bf16 stride: 144B -> 2-way alias (free), 16B aligned

__global__ __attribute__((amdgpu_waves_per_eu(3, 4))) __launch_bounds__(256)
void gemm_kernel(
    const float* __restrict__ obs, const float* __restrict__ hidden,
    const float* __restrict__ b_fc1,
    const float* __restrict__ b_ih, const float* __restrict__ b_hh,
    const float* __restrict__ w_fc2, const float* __restrict__ b_fc2,
    const void* __restrict__ wsv,
    float* q5,                       // ALIASED: obs_out (read) then q (write)
    float* __restrict__ h_out) {

  __shared__ __align__(16) __bf16 A_obs[ROWS_ * SOB_];
  __shared__ __align__(16) __bf16 A_x[ROWS_ * SXH_];
  __shared__ __align__(16) __bf16 A_h[ROWS_ * SXH_];

  const int tid  = threadIdx.x;
  const int wv   = tid >> 6;
  const int lane = tid & 63;
  const int l    = lane & 15;
  const int quad = lane >> 4;
  const int r0   = wv * 16;
  const long gr0 = (long)blockIdx.x * ROWS_;

  const __bf16* Wih = (const __bf16*)((const char*)wsv + 512);
  const __bf16* Whh = Wih + 192 * 64;
  const __bf16* Wf1 = Whh + 192 * 64;

  // ---- wave-local staging (no __syncthreads in this kernel) ----
  {
    const float* src = obs + (gr0 + r0) * OBS_DIM_;
    for (int it = lane; it < 16 * OBS_DIM_; it += 64) {
      int rr = it / OBS_DIM_; int cc = it - rr * OBS_DIM_;
      A_obs[(r0 + rr) * SOB_ + cc] = (__bf16)src[it];
    }
    const float* o5 = q5 + (gr0 + r0) * NL_;
    for (int it = lane; it < 16 * NL_; it += 64) {
      int rr = it / NL_; int cc = it - rr * NL_;
      A_obs[(r0 + rr) * SOB_ + 85 + cc] = (__bf16)o5[it];
    }
    for (int it = lane; it < 16 * 6; it += 64) {    // zero K-pad cols 90..95
      int rr = it / 6; int cc = it - rr * 6;
      A_obs[(r0 + rr) * SOB_ + 90 + cc] = (__bf16)0.0f;
    }
    const float* hsrc = hidden + (gr0 + r0) * HID_;
    for (int it = lane; it < 16 * HID_; it += 64) {
      int rr = it >> 6; int cc = it & 63;
      A_h[(r0 + rr) * SXH_ + cc] = (__bf16)hsrc[it];
    }
  }

  const f32x4 zero4 = {0.0f, 0.0f, 0.0f, 0.0f};

  // fc1: C[16x64] = A_obs[16x96] @ Wf1T
  f32x4 cx[4];
  #pragma unroll
  for (int nt = 0; nt < 4; ++nt) cx[nt] = zero4;
  #pragma unroll
  for (int ks = 0; ks < 3; ++ks) {
    bf16x8 af = *(const bf16x8*)&A_obs[(r0 + l) * SOB_ + ks * 32 + quad * 8];
    #pragma unroll
    for (int nt = 0; nt < 4; ++nt) {
      bf16x8 bf = *(const bf16x8*)&Wf1[(nt * 16 + l) * 96 + ks * 32 + quad * 8];
      cx[nt] = __builtin_amdgcn_mfma_f32_16x16x32_bf16(af, bf, cx[nt], 0, 0, 0);
    }
  }
  #pragma unroll
  for (int nt = 0; nt < 4; ++nt) {
    float bias = b_fc1[nt * 16 + l];
    #pragma unroll
    for (int rg = 0; rg < 4; ++rg) {
      float xv = fmaxf(cx[nt][rg] + bias, 0.0f);
      A_x[(r0 + quad * 4 + rg) * SXH_ + nt * 16 + l] = (__bf16)xv;
    }
  }

  // GRU GEMMs
  bf16x8 ax[2], ah[2];
  #pragma unroll
  for (int ks = 0; ks < 2; ++ks) {
    ax[ks] = *(const bf16x8*)&A_x[(r0 + l) * SXH_ + ks * 32 + quad * 8];
    ah[ks] = *(const bf16x8*)&A_h[(r0 + l) * SXH_ + ks * 32 + quad * 8];
  }
  f32x4 crz[8], cni[4], cnh[4];
  #pragma unroll
  for (int nt = 0; nt < 8; ++nt) crz[nt] = zero4;
  #pragma unroll
  for (int nt = 0; nt < 4; ++nt) { cni[nt] = zero4; cnh[nt] = zero4; }
  #pragma unroll
  for (int nt = 0; nt < 8; ++nt) {
    #pragma unroll
    for (int ks = 0; ks < 2; ++ks) {
      bf16x8 bi = *(const bf16x8*)&Wih[(nt * 16 + l) * 64 + ks * 32 + quad * 8];
      crz[nt] = __builtin_amdgcn_mfma_f32_16x16x32_bf16(ax[ks], bi, crz[nt], 0, 0, 0);
      bf16x8 bh = *(const bf16x8*)&Whh[(nt * 16 + l) * 64 + ks * 32 + quad * 8];
      crz[nt] = __builtin_amdgcn_mfma_f32_16x16x32_bf16(ah[ks], bh, crz[nt], 0, 0, 0);
    }
  }
  #pragma unroll
  for (int nt = 0; nt < 4; ++nt) {
    #pragma unroll
    for (int ks = 0; ks < 2; ++ks) {
      bf16x8 bi = *(const bf16x8*)&Wih[(128 + nt * 16 + l) * 64 + ks * 32 + quad * 8];
      cni[nt] = __builtin_amdgcn_mfma_f32_16x16x32_bf16(ax[ks], bi, cni[nt], 0, 0, 0);
      bf16x8 bh = *(const bf16x8*)&Whh[(128 + nt * 16 + l) * 64 + ks * 32 + quad * 8];
      cnh[nt] = __builtin_amdgcn_mfma_f32_16x16x32_bf16(ah[ks], bh, cnh[nt], 0, 0, 0);
    }
  }

  // epilogue (C layout: row = quad*4+rg, col = t*16+l)
  const long grow = gr0 + r0 + quad * 4;
  float qp[4][NACT_];
  #pragma unroll
  for (int rg = 0; rg < 4; ++rg)
    #pragma unroll
    for (int c = 0; c < NACT_; ++c) qp[rg][c] = 0.0f;

  #pragma unroll
  for (int t = 0; t < 4; ++t) {
    const int ur = t * 16 + l;
    float br  = b_ih[ur] + b_hh[ur];
    float bz  = b_ih[64 + ur] + b_hh[64 + ur];
    float bin = b_ih[128 + ur], bhn = b_hh[128 + ur];
    float w0 = w_fc2[ur * 5 + 0], w1 = w_fc2[ur * 5 + 1], w2 = w_fc2[ur * 5 + 2];
    float w3 = w_fc2[ur * 5 + 3], w4 = w_fc2[ur * 5 + 4];
    #pragma unroll
    for (int rg = 0; rg < 4; ++rg) {
      float rr = sigmoidf(crz[t][rg] + br);
      float zz = sigmoidf(crz[4 + t][rg] + bz);
      float nn = tanh_fast(cni[t][rg] + bin + rr * (cnh[t][rg] + bhn));
      float hold = hidden[(grow + rg) * HID_ + ur];
      float hn = (1.0f - zz) * nn + zz * hold;
      h_out[(grow + rg) * HID_ + ur] = hn;
      qp[rg][0] += hn * w0;
      qp[rg][1] += hn * w1;
      qp[rg][2] += hn * w2;
      qp[rg][3] += hn * w3;
      qp[rg][4] += hn * w4;
    }
  }
  #pragma unroll
  for (int m = 1; m < 16; m <<= 1) {
    #pragma unroll
    for (int rg = 0; rg < 4; ++rg)
      #pragma unroll
      for (int c = 0; c < NACT_; ++c) qp[rg][c] += __shfl_xor(qp[rg][c], m, 64);
  }
  if (l < NACT_) {
    #pragma unroll
    for (int rg = 0; rg < 4; ++rg) {
      float qv = qp[rg][0];
      if (l == 1) qv = qp[rg][1];
      if (l == 2) qv = qp[rg][2];
      if (l == 3) qv = qp[rg][3];
      if (l == 4) qv = qp[rg][4];
      q5[(grow + rg) * NACT_ + l] = qv + b_fc2[l];
    }
  }
}

}  // namespace

extern "C" void kernel_launch(void* const* d_in, const int* in_sizes, int n_in,
                              void* d_out, int out_size, void* d_ws, size_t ws_size,
                              hipStream_t stream) {
  const float* obs    = (const float*)d_in[0];
  const float* hidden = (const float*)d_in[1];
  const float* w_in0  = (const float*)d_in[2];
  const float* b_in0  = (const float*)d_in[3];
  const float* w_in1  = (const float*)d_in[4];
  const float* b_in1  = (const float*)d_in[5];
  const float* w_in2  = (const float*)d_in[6];
  const float* b_in2  = (const float*)d_in[7];
  const float* W      = (const float*)d_in[8];
  const float* a      = (const float*)d_in[9];
  const float* w_o1   = (const float*)d_in[10];
  const float* b_o1   = (const float*)d_in[11];
  const float* w_o2   = (const float*)d_in[12];
  const float* b_o2   = (const float*)d_in[13];
  const float* w_o3   = (const float*)d_in[14];
  const float* b_o3   = (const float*)d_in[15];
  const float* w_fc1  = (const float*)d_in[16];
  const float* b_fc1  = (const float*)d_in[17];
  const float* w_ih   = (const float*)d_in[18];
  const float* w_hh   = (const float*)d_in[19];
  const float* b_ih   = (const float*)d_in[20];
  const float* b_hh   = (const float*)d_in[21];
  const float* w_fc2  = (const float*)d_in[22];
  const float* b_fc2  = (const float*)d_in[23];

  float* q_out = (float*)d_out;                  // (B,5) -- also obs_out scratch
  float* h_out = q_out + (long)B_ * NACT_;       // (B,64)
  const float* Wa = (const float*)d_ws;

  prep_kernel<<<48, 256, 0, stream>>>(W, a, w_ih, w_hh, w_fc1, d_ws);
  front_kernel<<<B_ / FROWS_, 256, 0, stream>>>(
      obs, w_in0, b_in0, w_in1, b_in1, w_in2, b_in2,
      w_o1, b_o1, w_o2, b_o2, w_o3, b_o3, Wa, q_out);
  gemm_kernel<<<B_ / ROWS_, 256, 0, stream>>>(
      obs, hidden, b_fc1, b_ih, b_hh, w_fc2, b_fc2, d_ws, q_out, h_out);
}

// Round 7
// 256.575 us; speedup vs baseline: 1.3468x; 1.3468x over previous
//
#include <hip/hip_runtime.h>
#include <math.h>

namespace {

typedef __bf16 bf16x8 __attribute__((ext_vector_type(8)));
typedef float  f32x4  __attribute__((ext_vector_type(4)));
typedef float  f32x2  __attribute__((ext_vector_type(2)));

constexpr int B_      = 65536;
constexpr int OBS_DIM_= 85;
constexpr int NL_     = 5;
constexpr int NT_     = 10;
constexpr int HID_    = 64;
constexpr int NACT_   = 5;
constexpr float ALPHA_= 0.01f;

__device__ __forceinline__ float leaky(float x)    { return x > 0.0f ? x : ALPHA_ * x; }
__device__ __forceinline__ float sigmoidf(float x) { return 1.0f / (1.0f + __expf(-x)); }
__device__ __forceinline__ float tanh_fast(float x){ return 1.0f - 2.0f / (__expf(2.0f * x) + 1.0f); }

// ---------------------------------------------------------------------------
// Prep: Wa = W@a  ((h_mix@W)@a == h_mix@(W@a): kills the 64x64 matmul), plus
// bf16 weights for the MFMA kernel. ws: [0,512) Wa f32; Wih; Whh; Wf1T(64x96).
// ---------------------------------------------------------------------------
__global__ void prep_kernel(const float* __restrict__ W, const float* __restrict__ a,
                            const float* __restrict__ w_ih, const float* __restrict__ w_hh,
                            const float* __restrict__ w_fc1, void* __restrict__ ws) {
  float* Wa   = (float*)ws;
  __bf16* ih  = (__bf16*)((char*)ws + 512);
  __bf16* hh  = ih + 192 * 64;
  __bf16* f1t = hh + 192 * 64;
  const int tid = blockIdx.x * 256 + threadIdx.x;
  if (blockIdx.x == 0 && threadIdx.x < 64) {
    const int i = threadIdx.x;
    float s1 = 0.0f, s2 = 0.0f;
    #pragma unroll
    for (int j = 0; j < 64; ++j) {
      float w = W[i * 64 + j];
      s1 += w * a[j];
      s2 += w * a[64 + j];
    }
    Wa[i] = s1;
    Wa[64 + i] = s2;
  }
  const int stride = gridDim.x * 256;
  for (int i = tid; i < 192 * 64; i += stride) {
    ih[i] = (__bf16)w_ih[i];
    hh[i] = (__bf16)w_hh[i];
  }
  for (int i = tid; i < 64 * 96; i += stride) {
    int n = i / 96, k = i - 96 * n;
    f1t[i] = (__bf16)(k < 90 ? w_fc1[k * 64 + n] : 0.0f);
  }
}

// ======================= FRONT KERNEL =======================
// 32 lanes per row (2 INF units/lane), 8 rows per 256-thread block.
// Flat code, no device-fn array refs; peak live regs ~45 -> no spill even if
// the allocator pins 64 VGPR (observed r5/r6: it spills rather than exceed 64).
__global__ __launch_bounds__(256) void front_kernel(
    const float* __restrict__ obs,
    const float* __restrict__ w_in0, const float* __restrict__ b_in0,
    const float* __restrict__ w_in1, const float* __restrict__ b_in1,
    const float* __restrict__ w_in2, const float* __restrict__ b_in2,
    const float* __restrict__ w_o1, const float* __restrict__ b_o1,
    const float* __restrict__ w_o2, const float* __restrict__ b_o2,
    const float* __restrict__ w_o3, const float* __restrict__ b_o3,
    const float* __restrict__ Wa,
    float* __restrict__ out5) {

  __shared__ __align__(16) float s_obs[8][84];  // stride 84: 16B-aligned rows
  __shared__ float s_att[8][5][11];
  __shared__ float s_h1[8][5][33];   // stride 33: (33r+k)%32=(r+k)%32 -> r-varying lanes hit distinct banks
  __shared__ float s_h2[8][5][17];   // stride 17: same trick
  __shared__ float s_hp[8][5];

  const int tid    = threadIdx.x;
  const int wv     = tid >> 6;
  const int lane   = tid & 63;
  const int lane32 = lane & 31;
  const int rloc   = tid >> 5;              // 0..7 (two rows per wave)
  const long gr0   = (long)blockIdx.x * 8;

  // wave-local staging of cols 0..79 for this wave's two rows (no barriers:
  // every producer/consumer pair below is within one wave, in-order).
  {
    const float* src = obs + (gr0 + 2 * wv) * OBS_DIM_;
    #pragma unroll
    for (int c0 = 0; c0 < 3; ++c0) {
      int it = c0 * 64 + lane;
      if (it < 160) {
        int r = (it >= 80) ? 1 : 0;
        int c = it - 80 * r;
        s_obs[2 * wv + r][c] = src[r * OBS_DIM_ + c];
      }
    }
  }

  const int u0 = lane32 * 2;
  const float* orow = s_obs[rloc];
  const float wa1a = Wa[u0],      wa1b = Wa[u0 + 1];
  const float wa2a = Wa[64 + u0], wa2b = Wa[64 + u0 + 1];

  // ---- stage 1: partial Wh1/Wh2 over this lane's 2 INF units ----
  float p1[NT_], p2[NT_];
  #pragma unroll
  for (int t = 0; t < NT_; ++t) {
    const float* wc = (t < 5) ? w_in0 : (t < 9) ? w_in1 : w_in2;
    const float* bc = (t < 5) ? b_in0 : (t < 9) ? b_in1 : b_in2;
    const int ia = t * 8 + 4;             // feats 0..3 (never wraps)
    const int ib = (t * 8 + 8) % 80;      // feats 4..7 (wraps only at t=9)
    f32x4 oa = *(const f32x4*)&orow[ia];
    f32x4 ob = *(const f32x4*)&orow[ib];
    f32x2 bb = *(const f32x2*)&bc[u0];
    float z0 = bb[0], z1 = bb[1];
    #pragma unroll
    for (int f = 0; f < 4; ++f) {
      f32x2 w = *(const f32x2*)&wc[f * 64 + u0];   // CSE'd across t within class
      z0 += oa[f] * w[0];
      z1 += oa[f] * w[1];
    }
    #pragma unroll
    for (int f = 4; f < 8; ++f) {
      f32x2 w = *(const f32x2*)&wc[f * 64 + u0];
      z0 += ob[f - 4] * w[0];
      z1 += ob[f - 4] * w[1];
    }
    float h0 = leaky(z0), h1 = leaky(z1);
    p1[t] = h0 * wa1a + h1 * wa1b;
    p2[t] = h0 * wa2a + h1 * wa2b;
  }

  // butterfly across the 32-lane group (xor masks stay within the group)
  #pragma unroll
  for (int m = 1; m < 32; m <<= 1) {
    #pragma unroll
    for (int t = 0; t < NT_; ++t) {
      p1[t] += __shfl_xor(p1[t], m, 64);
      p2[t] += __shfl_xor(p2[t], m, 64);
    }
  }

  // att1 column softmax stats (all lanes, redundant, cheap)
  float colm[NL_], cols_[NL_];
  #pragma unroll
  for (int jj = 0; jj < NL_; ++jj) {
    float m = -1e30f, ev[NL_];
    #pragma unroll
    for (int k = 0; k < NL_; ++k) { ev[k] = leaky(p1[NL_ + jj] + p2[k]); m = fmaxf(m, ev[k]); }
    float s = 0.0f;
    #pragma unroll
    for (int k = 0; k < NL_; ++k) s += __expf(ev[k] - m);
    colm[jj] = m; cols_[jj] = s;
  }

  // lanes 0..4 of the group: attention row -> s_att
  if (lane32 < NL_) {
    const int r = lane32;
    float wh1_r = p1[0], wh2_r = p2[0];
    if (r == 1) { wh1_r = p1[1]; wh2_r = p2[1]; }
    if (r == 2) { wh1_r = p1[2]; wh2_r = p2[2]; }
    if (r == 3) { wh1_r = p1[3]; wh2_r = p2[3]; }
    if (r == 4) { wh1_r = p1[4]; wh2_r = p2[4]; }
    float ev[NL_], m = -1e30f;
    #pragma unroll
    for (int j = 0; j < NL_; ++j) { ev[j] = leaky(wh1_r + p2[NL_ + j]); m = fmaxf(m, ev[j]); }
    float a0[NL_], s = 0.0f;
    #pragma unroll
    for (int j = 0; j < NL_; ++j) { a0[j] = __expf(ev[j] - m); s += a0[j]; }
    float inv = 1.0f / s;
    #pragma unroll
    for (int j = 0; j < NL_; ++j) s_att[rloc][r][j] = a0[j] * inv;
    #pragma unroll
    for (int jj = 0; jj < NL_; ++jj) {
      float e = leaky(p1[NL_ + jj] + wh2_r);
      s_att[rloc][r][NL_ + jj] = __expf(e - colm[jj]) / cols_[jj];
    }
  }

  // h1: 5 att-rows x 32 units, one unit per lane per row
  #pragma unroll
  for (int r5 = 0; r5 < NL_; ++r5) {
    float z = b_o1[lane32];
    #pragma unroll
    for (int k = 0; k < NT_; ++k) z += s_att[rloc][r5][k] * w_o1[k * 32 + lane32];
    s_h1[rloc][r5][lane32] = leaky(z);
  }

  // h2: 5 x 16 = 80 items over 32 lanes
  #pragma unroll
  for (int b0 = 0; b0 < 3; ++b0) {
    int it = b0 * 32 + lane32;
    if (it < 80) {
      int r5 = it >> 4, c = it & 15;
      float z = b_o2[c];
      #pragma unroll
      for (int k = 0; k < 32; ++k) z += s_h1[rloc][r5][k] * w_o2[k * 16 + c];
      s_h2[rloc][r5][c] = leaky(z);
    }
  }

  // hp + softmax + store (lanes 0..4)
  float hp_own = 0.0f;
  if (lane32 < NL_) {
    float z3 = b_o3[0];
    #pragma unroll
    for (int k = 0; k < 16; ++k) z3 += s_h2[rloc][lane32][k] * w_o3[k];
    hp_own = leaky(z3);
    s_hp[rloc][lane32] = hp_own;
  }
  if (lane32 < NL_) {
    float m5 = -1e30f;
    #pragma unroll
    for (int j = 0; j < NL_; ++j) m5 = fmaxf(m5, s_hp[rloc][j]);
    float ssum = 0.0f;
    #pragma unroll
    for (int j = 0; j < NL_; ++j) ssum += __expf(s_hp[rloc][j] - m5);
    out5[(gr0 + rloc) * NL_ + lane32] = __expf(hp_own - m5) / ssum;
  }
}

// ======================= GEMM KERNEL (validated MFMA phase) =======================
constexpr int ROWS_ = 64;     // 4 waves x 16-row tiles
constexpr int SOB_  = 104;    // bf16 stride: 208B -> 2-way alias (free)
constexpr int SXH_  = 72;     // bf16 stride: 144B -> 2-way alias (free), 16B aligned

__global__ __launch_bounds__(256) void gemm_kernel(
    const float* __restrict__ obs, const float* __restrict__ hidden,
    const float* __restrict__ b_fc1,
    const float* __restrict__ b_ih, const float* __restrict__ b_hh,
    const float* __restrict__ w_fc2, const float* __restrict__ b_fc2,
    const void* __restrict__ wsv,
    float* q5,                       // ALIASED: obs_out (read) then q (write)
    float* __restrict__ h_out) {

  __shared__ __align__(16) __bf16 A_obs[ROWS_ * SOB_];
  __shared__ __align__(16) __bf16 A_x[ROWS_ * SXH_];
  __shared__ __align__(16) __bf16 A_h[ROWS_ * SXH_];

  const int tid  = threadIdx.x;
  const int wv   = tid >> 6;
  const int lane = tid & 63;
  const int l    = lane & 15;
  const int quad = lane >> 4;
  const int r0   = wv * 16;
  const long gr0 = (long)blockIdx.x * ROWS_;

  const __bf16* Wih = (const __bf16*)((const char*)wsv + 512);
  const __bf16* Whh = Wih + 192 * 64;
  const __bf16* Wf1 = Whh + 192 * 64;

  // ---- wave-local staging (no __syncthreads in this kernel) ----
  {
    const float* src = obs + (gr0 + r0) * OBS_DIM_;
    for (int it = lane; it < 16 * OBS_DIM_; it += 64) {
      int rr = it / OBS_DIM_; int cc = it - rr * OBS_DIM_;
      A_obs[(r0 + rr) * SOB_ + cc] = (__bf16)src[it];
    }
    const float* o5 = q5 + (gr0 + r0) * NL_;
    for (int it = lane; it < 16 * NL_; it += 64) {
      int rr = it / NL_; int cc = it - rr * NL_;
      A_obs[(r0 + rr) * SOB_ + 85 + cc] = (__bf16)o5[it];
    }
    for (int it = lane; it < 16 * 6; it += 64) {    // zero K-pad cols 90..95
      int rr = it / 6; int cc = it - rr * 6;
      A_obs[(r0 + rr) * SOB_ + 90 + cc] = (__bf16)0.0f;
    }
    const float* hsrc = hidden + (gr0 + r0) * HID_;
    for (int it = lane; it < 16 * HID_; it += 64) {
      int rr = it >> 6; int cc = it & 63;
      A_h[(r0 + rr) * SXH_ + cc] = (__bf16)hsrc[it];
    }
  }

  const f32x4 zero4 = {0.0f, 0.0f, 0.0f, 0.0f};

  // fc1: C[16x64] = A_obs[16x96] @ Wf1T
  f32x4 cx[4];
  #pragma unroll
  for (int nt = 0; nt < 4; ++nt) cx[nt] = zero4;
  #pragma unroll
  for (int ks = 0; ks < 3; ++ks) {
    bf16x8 af = *(const bf16x8*)&A_obs[(r0 + l) * SOB_ + ks * 32 + quad * 8];
    #pragma unroll
    for (int nt = 0; nt < 4; ++nt) {
      bf16x8 bf = *(const bf16x8*)&Wf1[(nt * 16 + l) * 96 + ks * 32 + quad * 8];
      cx[nt] = __builtin_amdgcn_mfma_f32_16x16x32_bf16(af, bf, cx[nt], 0, 0, 0);
    }
  }
  #pragma unroll
  for (int nt = 0; nt < 4; ++nt) {
    float bias = b_fc1[nt * 16 + l];
    #pragma unroll
    for (int rg = 0; rg < 4; ++rg) {
      float xv = fmaxf(cx[nt][rg] + bias, 0.0f);
      A_x[(r0 + quad * 4 + rg) * SXH_ + nt * 16 + l] = (__bf16)xv;
    }
  }

  // GRU GEMMs
  bf16x8 ax[2], ah[2];
  #pragma unroll
  for (int ks = 0; ks < 2; ++ks) {
    ax[ks] = *(const bf16x8*)&A_x[(r0 + l) * SXH_ + ks * 32 + quad * 8];
    ah[ks] = *(const bf16x8*)&A_h[(r0 + l) * SXH_ + ks * 32 + quad * 8];
  }
  f32x4 crz[8], cni[4], cnh[4];
  #pragma unroll
  for (int nt = 0; nt < 8; ++nt) crz[nt] = zero4;
  #pragma unroll
  for (int nt = 0; nt < 4; ++nt) { cni[nt] = zero4; cnh[nt] = zero4; }
  #pragma unroll
  for (int nt = 0; nt < 8; ++nt) {
    #pragma unroll
    for (int ks = 0; ks < 2; ++ks) {
      bf16x8 bi = *(const bf16x8*)&Wih[(nt * 16 + l) * 64 + ks * 32 + quad * 8];
      crz[nt] = __builtin_amdgcn_mfma_f32_16x16x32_bf16(ax[ks], bi, crz[nt], 0, 0, 0);
      bf16x8 bh = *(const bf16x8*)&Whh[(nt * 16 + l) * 64 + ks * 32 + quad * 8];
      crz[nt] = __builtin_amdgcn_mfma_f32_16x16x32_bf16(ah[ks], bh, crz[nt], 0, 0, 0);
    }
  }
  #pragma unroll
  for (int nt = 0; nt < 4; ++nt) {
    #pragma unroll
    for (int ks = 0; ks < 2; ++ks) {
      bf16x8 bi = *(const bf16x8*)&Wih[(128 + nt * 16 + l) * 64 + ks * 32 + quad * 8];
      cni[nt] = __builtin_amdgcn_mfma_f32_16x16x32_bf16(ax[ks], bi, cni[nt], 0, 0, 0);
      bf16x8 bh = *(const bf16x8*)&Whh[(128 + nt * 16 + l) * 64 + ks * 32 + quad * 8];
      cnh[nt] = __builtin_amdgcn_mfma_f32_16x16x32_bf16(ah[ks], bh, cnh[nt], 0, 0, 0);
    }
  }

  // epilogue (C layout: row = quad*4+rg, col = t*16+l)
  const long grow = gr0 + r0 + quad * 4;
  float qp[4][NACT_];
  #pragma unroll
  for (int rg = 0; rg < 4; ++rg)
    #pragma unroll
    for (int c = 0; c < NACT_; ++c) qp[rg][c] = 0.0f;

  #pragma unroll
  for (int t = 0; t < 4; ++t) {
    const int ur = t * 16 + l;
    float br  = b_ih[ur] + b_hh[ur];
    float bz  = b_ih[64 + ur] + b_hh[64 + ur];
    float bin = b_ih[128 + ur], bhn = b_hh[128 + ur];
    float w0 = w_fc2[ur * 5 + 0], w1 = w_fc2[ur * 5 + 1], w2 = w_fc2[ur * 5 + 2];
    float w3 = w_fc2[ur * 5 + 3], w4 = w_fc2[ur * 5 + 4];
    #pragma unroll
    for (int rg = 0; rg < 4; ++rg) {
      float rr = sigmoidf(crz[t][rg] + br);
      float zz = sigmoidf(crz[4 + t][rg] + bz);
      float nn = tanh_fast(cni[t][rg] + bin + rr * (cnh[t][rg] + bhn));
      float hold = hidden[(grow + rg) * HID_ + ur];
      float hn = (1.0f - zz) * nn + zz * hold;
      h_out[(grow + rg) * HID_ + ur] = hn;
      qp[rg][0] += hn * w0;
      qp[rg][1] += hn * w1;
      qp[rg][2] += hn * w2;
      qp[rg][3] += hn * w3;
      qp[rg][4] += hn * w4;
    }
  }
  #pragma unroll
  for (int m = 1; m < 16; m <<= 1) {
    #pragma unroll
    for (int rg = 0; rg < 4; ++rg)
      #pragma unroll
      for (int c = 0; c < NACT_; ++c) qp[rg][c] += __shfl_xor(qp[rg][c], m, 64);
  }
  if (l < NACT_) {
    #pragma unroll
    for (int rg = 0; rg < 4; ++rg) {
      float qv = qp[rg][0];
      if (l == 1) qv = qp[rg][1];
      if (l == 2) qv = qp[rg][2];
      if (l == 3) qv = qp[rg][3];
      if (l == 4) qv = qp[rg][4];
      q5[(grow + rg) * NACT_ + l] = qv + b_fc2[l];
    }
  }
}

}  // namespace

extern "C" void kernel_launch(void* const* d_in, const int* in_sizes, int n_in,
                              void* d_out, int out_size, void* d_ws, size_t ws_size,
                              hipStream_t stream) {
  const float* obs    = (const float*)d_in[0];
  const float* hidden = (const float*)d_in[1];
  const float* w_in0  = (const float*)d_in[2];
  const float* b_in0  = (const float*)d_in[3];
  const float* w_in1  = (const float*)d_in[4];
  const float* b_in1  = (const float*)d_in[5];
  const float* w_in2  = (const float*)d_in[6];
  const float* b_in2  = (const float*)d_in[7];
  const float* W      = (const float*)d_in[8];
  const float* a      = (const float*)d_in[9];
  const float* w_o1   = (const float*)d_in[10];
  const float* b_o1   = (const float*)d_in[11];
  const float* w_o2   = (const float*)d_in[12];
  const float* b_o2   = (const float*)d_in[13];
  const float* w_o3   = (const float*)d_in[14];
  const float* b_o3   = (const float*)d_in[15];
  const float* w_fc1  = (const float*)d_in[16];
  const float* b_fc1  = (const float*)d_in[17];
  const float* w_ih   = (const float*)d_in[18];
  const float* w_hh   = (const float*)d_in[19];
  const float* b_ih   = (const float*)d_in[20];
  const float* b_hh   = (const float*)d_in[21];
  const float* w_fc2  = (const float*)d_in[22];
  const float* b_fc2  = (const float*)d_in[23];

  float* q_out = (float*)d_out;                  // (B,5) -- also obs_out scratch
  float* h_out = q_out + (long)B_ * NACT_;       // (B,64)
  const float* Wa = (const float*)d_ws;

  prep_kernel<<<48, 256, 0, stream>>>(W, a, w_ih, w_hh, w_fc1, d_ws);
  front_kernel<<<B_ / 8, 256, 0, stream>>>(
      obs, w_in0, b_in0, w_in1, b_in1, w_in2, b_in2,
      w_o1, b_o1, w_o2, b_o2, w_o3, b_o3, Wa, q_out);
  gemm_kernel<<<B_ / ROWS_, 256, 0, stream>>>(
      obs, hidden, b_fc1, b_ih, b_hh, w_fc2, b_fc2, d_ws, q_out, h_out);
}

// Round 8
// 240.148 us; speedup vs baseline: 1.4389x; 1.0684x over previous
//
#include <hip/hip_runtime.h>
#include <math.h>

namespace {

typedef __bf16 bf16x8 __attribute__((ext_vector_type(8)));
typedef __bf16 bf16x4 __attribute__((ext_vector_type(4)));
typedef float  f32x4  __attribute__((ext_vector_type(4)));
typedef float  f32x2  __attribute__((ext_vector_type(2)));

constexpr int B_      = 65536;
constexpr int OBS_DIM_= 85;
constexpr int NL_     = 5;
constexpr int NT_     = 10;
constexpr int HID_    = 64;
constexpr int NACT_   = 5;
constexpr float ALPHA_= 0.01f;

__device__ __forceinline__ float leaky(float x)    { return x > 0.0f ? x : ALPHA_ * x; }
__device__ __forceinline__ float sigmoidf(float x) { return 1.0f / (1.0f + __expf(-x)); }
__device__ __forceinline__ float tanh_fast(float x){ return 1.0f - 2.0f / (__expf(2.0f * x) + 1.0f); }

// ---------------------------------------------------------------------------
// Prep: Wa = W@a  ((h_mix@W)@a == h_mix@(W@a): kills the 64x64 matmul), plus
// bf16 weights for the MFMA kernel. ws: [0,512) Wa f32; Wih; Whh; Wf1T(64x96).
// ---------------------------------------------------------------------------
__global__ void prep_kernel(const float* __restrict__ W, const float* __restrict__ a,
                            const float* __restrict__ w_ih, const float* __restrict__ w_hh,
                            const float* __restrict__ w_fc1, void* __restrict__ ws) {
  float* Wa   = (float*)ws;
  __bf16* ih  = (__bf16*)((char*)ws + 512);
  __bf16* hh  = ih + 192 * 64;
  __bf16* f1t = hh + 192 * 64;
  const int tid = blockIdx.x * 256 + threadIdx.x;
  if (blockIdx.x == 0 && threadIdx.x < 64) {
    const int i = threadIdx.x;
    float s1 = 0.0f, s2 = 0.0f;
    #pragma unroll
    for (int j = 0; j < 64; ++j) {
      float w = W[i * 64 + j];
      s1 += w * a[j];
      s2 += w * a[64 + j];
    }
    Wa[i] = s1;
    Wa[64 + i] = s2;
  }
  const int stride = gridDim.x * 256;
  for (int i = tid; i < 192 * 64; i += stride) {
    ih[i] = (__bf16)w_ih[i];
    hh[i] = (__bf16)w_hh[i];
  }
  for (int i = tid; i < 64 * 96; i += stride) {
    int n = i / 96, k = i - 96 * n;
    f1t[i] = (__bf16)(k < 90 ? w_fc1[k * 64 + n] : 0.0f);
  }
}

// ======================= FRONT KERNEL =======================
// 32 lanes/row, 8 rows/block. KEY (r7 post-mortem): never hold p1[10]/p2[10]
// in registers -- per-t scalars are butterflied immediately and parked in LDS,
// so peak live regs ~45 and the allocator's 64-VGPR target can't spill.
// All producer/consumer pairs are same-wave -> zero barriers after staging.

#define STAGE1(WC, BC, T0, T1)                                               \
  {                                                                          \
    const f32x2 bb = *(const f32x2*)&BC[u0];                                 \
    f32x2 w0 = *(const f32x2*)&WC[0 * 64 + u0];                              \
    f32x2 w1 = *(const f32x2*)&WC[1 * 64 + u0];                              \
    f32x2 w2 = *(const f32x2*)&WC[2 * 64 + u0];                              \
    f32x2 w3 = *(const f32x2*)&WC[3 * 64 + u0];                              \
    f32x2 w4 = *(const f32x2*)&WC[4 * 64 + u0];                              \
    f32x2 w5 = *(const f32x2*)&WC[5 * 64 + u0];                              \
    f32x2 w6 = *(const f32x2*)&WC[6 * 64 + u0];                              \
    f32x2 w7 = *(const f32x2*)&WC[7 * 64 + u0];                              \
    _Pragma("unroll")                                                        \
    for (int t = T0; t < T1; ++t) {                                          \
      const int ia = t * 8 + 4;                                              \
      const int ib = (t * 8 + 8) % 80;                                       \
      f32x4 oa = *(const f32x4*)&orow[ia];                                   \
      f32x4 ob = *(const f32x4*)&orow[ib];                                   \
      float z0 = bb[0], z1 = bb[1];                                          \
      z0 += oa[0]*w0[0] + oa[1]*w1[0] + oa[2]*w2[0] + oa[3]*w3[0]            \
          + ob[0]*w4[0] + ob[1]*w5[0] + ob[2]*w6[0] + ob[3]*w7[0];           \
      z1 += oa[0]*w0[1] + oa[1]*w1[1] + oa[2]*w2[1] + oa[3]*w3[1]            \
          + ob[0]*w4[1] + ob[1]*w5[1] + ob[2]*w6[1] + ob[3]*w7[1];           \
      float h0 = leaky(z0), h1 = leaky(z1);                                  \
      float p1t = h0 * wa1a + h1 * wa1b;                                     \
      float p2t = h0 * wa2a + h1 * wa2b;                                     \
      p1t += __shfl_xor(p1t, 1, 64);   p2t += __shfl_xor(p2t, 1, 64);        \
      p1t += __shfl_xor(p1t, 2, 64);   p2t += __shfl_xor(p2t, 2, 64);        \
      p1t += __shfl_xor(p1t, 4, 64);   p2t += __shfl_xor(p2t, 4, 64);        \
      p1t += __shfl_xor(p1t, 8, 64);   p2t += __shfl_xor(p2t, 8, 64);        \
      p1t += __shfl_xor(p1t, 16, 64);  p2t += __shfl_xor(p2t, 16, 64);       \
      if (lane32 == 0) { s_wh1[rloc][t] = p1t; s_wh2[rloc][t] = p2t; }       \
    }                                                                        \
  }

__global__ __launch_bounds__(256) void front_kernel(
    const float* __restrict__ obs,
    const float* __restrict__ w_in0, const float* __restrict__ b_in0,
    const float* __restrict__ w_in1, const float* __restrict__ b_in1,
    const float* __restrict__ w_in2, const float* __restrict__ b_in2,
    const float* __restrict__ w_o1, const float* __restrict__ b_o1,
    const float* __restrict__ w_o2, const float* __restrict__ b_o2,
    const float* __restrict__ w_o3, const float* __restrict__ b_o3,
    const float* __restrict__ Wa,
    float* __restrict__ out5) {

  __shared__ __align__(16) float s_obs[8][84];
  __shared__ float s_wh1[8][12], s_wh2[8][12];
  __shared__ float s_colm[8][6], s_cols[8][6];
  __shared__ float s_att[8][5][11];
  __shared__ float s_h1[8][5][33];   // stride 33: r5-varying lanes hit distinct banks
  __shared__ float s_h2[8][5][17];
  __shared__ float s_hp[8][6];

  const int tid    = threadIdx.x;
  const int wv     = tid >> 6;
  const int lane   = tid & 63;
  const int lane32 = lane & 31;
  const int rloc   = tid >> 5;              // 0..7 (two rows per wave)
  const long gr0   = (long)blockIdx.x * 8;

  // wave-local staging of cols 0..79 for this wave's two rows
  {
    const float* src = obs + (gr0 + 2 * wv) * OBS_DIM_;
    #pragma unroll
    for (int c0 = 0; c0 < 3; ++c0) {
      int it = c0 * 64 + lane;
      if (it < 160) {
        int r = (it >= 80) ? 1 : 0;
        int c = it - 80 * r;
        s_obs[2 * wv + r][c] = src[r * OBS_DIM_ + c];
      }
    }
  }

  const int u0 = lane32 * 2;
  const float* orow = s_obs[rloc];
  const float wa1a = Wa[u0],      wa1b = Wa[u0 + 1];
  const float wa2a = Wa[64 + u0], wa2b = Wa[64 + u0 + 1];

  STAGE1(w_in0, b_in0, 0, 5)
  STAGE1(w_in1, b_in1, 5, 9)
  STAGE1(w_in2, b_in2, 9, 10)

  // lanes 5..9: att1 column softmax stats for column jj = lane32-5
  if (lane32 >= 5 && lane32 < 10) {
    const int jj = lane32 - 5;
    float w1v = s_wh1[rloc][NL_ + jj];
    float ev[NL_], m = -1e30f;
    #pragma unroll
    for (int k = 0; k < NL_; ++k) { ev[k] = leaky(w1v + s_wh2[rloc][k]); m = fmaxf(m, ev[k]); }
    float s = 0.0f;
    #pragma unroll
    for (int k = 0; k < NL_; ++k) s += __expf(ev[k] - m);
    s_colm[rloc][jj] = m;
    s_cols[rloc][jj] = s;
  }

  // lanes 0..4: attention row r = lane32 -> s_att
  if (lane32 < NL_) {
    const int r = lane32;
    const float wh1_r = s_wh1[rloc][r];
    const float wh2_r = s_wh2[rloc][r];
    float ev[NL_], m = -1e30f;
    #pragma unroll
    for (int j = 0; j < NL_; ++j) { ev[j] = leaky(wh1_r + s_wh2[rloc][NL_ + j]); m = fmaxf(m, ev[j]); }
    float a0[NL_], s = 0.0f;
    #pragma unroll
    for (int j = 0; j < NL_; ++j) { a0[j] = __expf(ev[j] - m); s += a0[j]; }
    float inv = 1.0f / s;
    #pragma unroll
    for (int j = 0; j < NL_; ++j) s_att[rloc][r][j] = a0[j] * inv;
    #pragma unroll
    for (int jj = 0; jj < NL_; ++jj) {
      float e = leaky(s_wh1[rloc][NL_ + jj] + wh2_r);
      s_att[rloc][r][NL_ + jj] = __expf(e - s_colm[rloc][jj]) / s_cols[rloc][jj];
    }
  }

  // h1: 5 att-rows x 32 units, one unit per lane per row
  #pragma unroll
  for (int r5 = 0; r5 < NL_; ++r5) {
    float z = b_o1[lane32];
    #pragma unroll
    for (int k = 0; k < NT_; ++k) z += s_att[rloc][r5][k] * w_o1[k * 32 + lane32];
    s_h1[rloc][r5][lane32] = leaky(z);
  }

  // h2: 5 x 16 = 80 items over 32 lanes
  #pragma unroll
  for (int b0 = 0; b0 < 3; ++b0) {
    int it = b0 * 32 + lane32;
    if (it < 80) {
      int r5 = it >> 4, c = it & 15;
      float z = b_o2[c];
      #pragma unroll
      for (int k = 0; k < 32; ++k) z += s_h1[rloc][r5][k] * w_o2[k * 16 + c];
      s_h2[rloc][r5][c] = leaky(z);
    }
  }

  // hp + softmax + store (lanes 0..4)
  if (lane32 < NL_) {
    float z3 = b_o3[0];
    #pragma unroll
    for (int k = 0; k < 16; ++k) z3 += s_h2[rloc][lane32][k] * w_o3[k];
    float hp_own = leaky(z3);
    s_hp[rloc][lane32] = hp_own;
    float m5 = -1e30f;
    #pragma unroll
    for (int j = 0; j < NL_; ++j) m5 = fmaxf(m5, s_hp[rloc][j]);
    float ssum = 0.0f;
    #pragma unroll
    for (int j = 0; j < NL_; ++j) ssum += __expf(s_hp[rloc][j] - m5);
    out5[(gr0 + rloc) * NL_ + lane32] = __expf(hp_own - m5) / ssum;
  }
}

// ======================= GEMM KERNEL (validated MFMA phase) =======================
constexpr int ROWS_ = 64;     // 4 waves x 16-row tiles
constexpr int SOB_  = 104;    // bf16 stride: 208B -> 2-way alias (free)
constexpr int SXH_  = 72;     // bf16 stride: 144B -> 2-way alias (free), 16B aligned

__global__ __launch_bounds__(256) void gemm_kernel(
    const float* __restrict__ obs, const float* __restrict__ hidden,
    const float* __restrict__ b_fc1,
    const float* __restrict__ b_ih, const float* __restrict__ b_hh,
    const float* __restrict__ w_fc2, const float* __restrict__ b_fc2,
    const void* __restrict__ wsv,
    float* q5,                       // ALIASED: obs_out (read) then q (write)
    float* __restrict__ h_out) {

  __shared__ __align__(16) __bf16 A_obs[ROWS_ * SOB_];
  __shared__ __align__(16) __bf16 A_x[ROWS_ * SXH_];
  __shared__ __align__(16) __bf16 A_h[ROWS_ * SXH_];

  const int tid  = threadIdx.x;
  const int wv   = tid >> 6;
  const int lane = tid & 63;
  const int l    = lane & 15;
  const int quad = lane >> 4;
  const int r0   = wv * 16;
  const long gr0 = (long)blockIdx.x * ROWS_;

  const __bf16* Wih = (const __bf16*)((const char*)wsv + 512);
  const __bf16* Whh = Wih + 192 * 64;
  const __bf16* Wf1 = Whh + 192 * 64;

  // ---- wave-local staging (no __syncthreads in this kernel) ----
  {
    // obs: 16 rows x 85 = 1360 f32 = 340 f32x4, vectorized global reads
    const float* src = obs + (gr0 + r0) * OBS_DIM_;
    #pragma unroll
    for (int k = 0; k < 6; ++k) {
      int idx = lane + 64 * k;
      if (idx < 340) {
        f32x4 v = *(const f32x4*)&src[idx * 4];
        #pragma unroll
        for (int e = 0; e < 4; ++e) {
          int fe = idx * 4 + e;
          int rr = fe / 85, cc = fe - 85 * rr;
          A_obs[(r0 + rr) * SOB_ + cc] = (__bf16)v[e];
        }
      }
    }
    const float* o5 = q5 + (gr0 + r0) * NL_;
    for (int it = lane; it < 16 * NL_; it += 64) {
      int rr = it / NL_; int cc = it - rr * NL_;
      A_obs[(r0 + rr) * SOB_ + 85 + cc] = (__bf16)o5[it];
    }
    for (int it = lane; it < 16 * 6; it += 64) {    // zero K-pad cols 90..95
      int rr = it / 6; int cc = it - rr * 6;
      A_obs[(r0 + rr) * SOB_ + 90 + cc] = (__bf16)0.0f;
    }
    // hidden: 16 rows x 64 = 1024 f32 = 256 f32x4; rows never straddled
    const float* hsrc = hidden + (gr0 + r0) * HID_;
    #pragma unroll
    for (int k = 0; k < 4; ++k) {
      int f4 = lane + 64 * k;          // f32x4 index 0..255
      f32x4 v = *(const f32x4*)&hsrc[f4 * 4];
      int rr = f4 >> 4;
      int cc = (f4 & 15) * 4;
      bf16x4 b;
      b[0] = (__bf16)v[0]; b[1] = (__bf16)v[1];
      b[2] = (__bf16)v[2]; b[3] = (__bf16)v[3];
      *(bf16x4*)&A_h[(r0 + rr) * SXH_ + cc] = b;
    }
  }

  const f32x4 zero4 = {0.0f, 0.0f, 0.0f, 0.0f};

  // fc1: C[16x64] = A_obs[16x96] @ Wf1T
  f32x4 cx[4];
  #pragma unroll
  for (int nt = 0; nt < 4; ++nt) cx[nt] = zero4;
  #pragma unroll
  for (int ks = 0; ks < 3; ++ks) {
    bf16x8 af = *(const bf16x8*)&A_obs[(r0 + l) * SOB_ + ks * 32 + quad * 8];
    #pragma unroll
    for (int nt = 0; nt < 4; ++nt) {
      bf16x8 bf = *(const bf16x8*)&Wf1[(nt * 16 + l) * 96 + ks * 32 + quad * 8];
      cx[nt] = __builtin_amdgcn_mfma_f32_16x16x32_bf16(af, bf, cx[nt], 0, 0, 0);
    }
  }
  #pragma unroll
  for (int nt = 0; nt < 4; ++nt) {
    float bias = b_fc1[nt * 16 + l];
    #pragma unroll
    for (int rg = 0; rg < 4; ++rg) {
      float xv = fmaxf(cx[nt][rg] + bias, 0.0f);
      A_x[(r0 + quad * 4 + rg) * SXH_ + nt * 16 + l] = (__bf16)xv;
    }
  }

  // GRU GEMMs
  bf16x8 ax[2], ah[2];
  #pragma unroll
  for (int ks = 0; ks < 2; ++ks) {
    ax[ks] = *(const bf16x8*)&A_x[(r0 + l) * SXH_ + ks * 32 + quad * 8];
    ah[ks] = *(const bf16x8*)&A_h[(r0 + l) * SXH_ + ks * 32 + quad * 8];
  }
  f32x4 crz[8], cni[4], cnh[4];
  #pragma unroll
  for (int nt = 0; nt < 8; ++nt) crz[nt] = zero4;
  #pragma unroll
  for (int nt = 0; nt < 4; ++nt) { cni[nt] = zero4; cnh[nt] = zero4; }
  #pragma unroll
  for (int nt = 0; nt < 8; ++nt) {
    #pragma unroll
    for (int ks = 0; ks < 2; ++ks) {
      bf16x8 bi = *(const bf16x8*)&Wih[(nt * 16 + l) * 64 + ks * 32 + quad * 8];
      crz[nt] = __builtin_amdgcn_mfma_f32_16x16x32_bf16(ax[ks], bi, crz[nt], 0, 0, 0);
      bf16x8 bh = *(const bf16x8*)&Whh[(nt * 16 + l) * 64 + ks * 32 + quad * 8];
      crz[nt] = __builtin_amdgcn_mfma_f32_16x16x32_bf16(ah[ks], bh, crz[nt], 0, 0, 0);
    }
  }
  #pragma unroll
  for (int nt = 0; nt < 4; ++nt) {
    #pragma unroll
    for (int ks = 0; ks < 2; ++ks) {
      bf16x8 bi = *(const bf16x8*)&Wih[(128 + nt * 16 + l) * 64 + ks * 32 + quad * 8];
      cni[nt] = __builtin_amdgcn_mfma_f32_16x16x32_bf16(ax[ks], bi, cni[nt], 0, 0, 0);
      bf16x8 bh = *(const bf16x8*)&Whh[(128 + nt * 16 + l) * 64 + ks * 32 + quad * 8];
      cnh[nt] = __builtin_amdgcn_mfma_f32_16x16x32_bf16(ah[ks], bh, cnh[nt], 0, 0, 0);
    }
  }

  // epilogue (C layout: row = quad*4+rg, col = t*16+l)
  const long grow = gr0 + r0 + quad * 4;
  float qp[4][NACT_];
  #pragma unroll
  for (int rg = 0; rg < 4; ++rg)
    #pragma unroll
    for (int c = 0; c < NACT_; ++c) qp[rg][c] = 0.0f;

  #pragma unroll
  for (int t = 0; t < 4; ++t) {
    const int ur = t * 16 + l;
    float br  = b_ih[ur] + b_hh[ur];
    float bz  = b_ih[64 + ur] + b_hh[64 + ur];
    float bin = b_ih[128 + ur], bhn = b_hh[128 + ur];
    float w0 = w_fc2[ur * 5 + 0], w1 = w_fc2[ur * 5 + 1], w2 = w_fc2[ur * 5 + 2];
    float w3 = w_fc2[ur * 5 + 3], w4 = w_fc2[ur * 5 + 4];
    #pragma unroll
    for (int rg = 0; rg < 4; ++rg) {
      float rr = sigmoidf(crz[t][rg] + br);
      float zz = sigmoidf(crz[4 + t][rg] + bz);
      float nn = tanh_fast(cni[t][rg] + bin + rr * (cnh[t][rg] + bhn));
      float hold = hidden[(grow + rg) * HID_ + ur];
      float hn = (1.0f - zz) * nn + zz * hold;
      h_out[(grow + rg) * HID_ + ur] = hn;
      qp[rg][0] += hn * w0;
      qp[rg][1] += hn * w1;
      qp[rg][2] += hn * w2;
      qp[rg][3] += hn * w3;
      qp[rg][4] += hn * w4;
    }
  }
  #pragma unroll
  for (int m = 1; m < 16; m <<= 1) {
    #pragma unroll
    for (int rg = 0; rg < 4; ++rg)
      #pragma unroll
      for (int c = 0; c < NACT_; ++c) qp[rg][c] += __shfl_xor(qp[rg][c], m, 64);
  }
  if (l < NACT_) {
    #pragma unroll
    for (int rg = 0; rg < 4; ++rg) {
      float qv = qp[rg][0];
      if (l == 1) qv = qp[rg][1];
      if (l == 2) qv = qp[rg][2];
      if (l == 3) qv = qp[rg][3];
      if (l == 4) qv = qp[rg][4];
      q5[(grow + rg) * NACT_ + l] = qv + b_fc2[l];
    }
  }
}

}  // namespace

extern "C" void kernel_launch(void* const* d_in, const int* in_sizes, int n_in,
                              void* d_out, int out_size, void* d_ws, size_t ws_size,
                              hipStream_t stream) {
  const float* obs    = (const float*)d_in[0];
  const float* hidden = (const float*)d_in[1];
  const float* w_in0  = (const float*)d_in[2];
  const float* b_in0  = (const float*)d_in[3];
  const float* w_in1  = (const float*)d_in[4];
  const float* b_in1  = (const float*)d_in[5];
  const float* w_in2  = (const float*)d_in[6];
  const float* b_in2  = (const float*)d_in[7];
  const float* W      = (const float*)d_in[8];
  const float* a      = (const float*)d_in[9];
  const float* w_o1   = (const float*)d_in[10];
  const float* b_o1   = (const float*)d_in[11];
  const float* w_o2   = (const float*)d_in[12];
  const float* b_o2   = (const float*)d_in[13];
  const float* w_o3   = (const float*)d_in[14];
  const float* b_o3   = (const float*)d_in[15];
  const float* w_fc1  = (const float*)d_in[16];
  const float* b_fc1  = (const float*)d_in[17];
  const float* w_ih   = (const float*)d_in[18];
  const float* w_hh   = (const float*)d_in[19];
  const float* b_ih   = (const float*)d_in[20];
  const float* b_hh   = (const float*)d_in[21];
  const float* w_fc2  = (const float*)d_in[22];
  const float* b_fc2  = (const float*)d_in[23];

  float* q_out = (float*)d_out;                  // (B,5) -- also obs_out scratch
  float* h_out = q_out + (long)B_ * NACT_;       // (B,64)
  const float* Wa = (const float*)d_ws;

  prep_kernel<<<48, 256, 0, stream>>>(W, a, w_ih, w_hh, w_fc1, d_ws);
  front_kernel<<<B_ / 8, 256, 0, stream>>>(
      obs, w_in0, b_in0, w_in1, b_in1, w_in2, b_in2,
      w_o1, b_o1, w_o2, b_o2, w_o3, b_o3, Wa, q_out);
  gemm_kernel<<<B_ / ROWS_, 256, 0, stream>>>(
      obs, hidden, b_fc1, b_ih, b_hh, w_fc2, b_fc2, d_ws, q_out, h_out);
}